// Round 1
// baseline (885.706 us; speedup 1.0000x reference)
//
#include <hip/hip_runtime.h>
#include <hip/hip_bf16.h>

#define BETA_C 0.04f
#define EPS_LOW_C 0.2f
#define EPS_HIGH_C 0.2f

static constexpr int B_ = 4, S_ = 1024, H_ = 2048, V_ = 32000;
static constexpr int M_ = B_ * S_;          // 4096 rows (tokens)
static constexpr int BM = 128, BN = 128, BK = 64;
static constexpr int NRB = M_ / BM;         // 32 row blocks
static constexpr int NCB = V_ / BN;         // 250 col blocks

typedef __attribute__((ext_vector_type(8))) short short8;
typedef __attribute__((ext_vector_type(4))) float f32x4;

__device__ __forceinline__ unsigned short f2bf(float f) {
    unsigned u = __builtin_bit_cast(unsigned, f);
    unsigned r = 0x7FFFu + ((u >> 16) & 1u);
    return (unsigned short)((u + r) >> 16);
}

__device__ __forceinline__ void gload_lds16(const unsigned short* g, unsigned short* l) {
    __builtin_amdgcn_global_load_lds(
        (const __attribute__((address_space(1))) unsigned int*)g,
        (__attribute__((address_space(3))) unsigned int*)l, 16, 0, 0);
}

// ---------------- fp32 -> bf16 conversion (vectorized) ----------------
__global__ void cvt_kernel(const float* __restrict__ in, unsigned short* __restrict__ out, int n4) {
    int i = blockIdx.x * blockDim.x + threadIdx.x;
    int stride = gridDim.x * blockDim.x;
    for (; i < n4; i += stride) {
        float4 v = reinterpret_cast<const float4*>(in)[i];
        ushort4 o;
        o.x = f2bf(v.x); o.y = f2bf(v.y); o.z = f2bf(v.z); o.w = f2bf(v.w);
        reinterpret_cast<ushort4*>(out)[i] = o;
    }
}

// ---------------- fused GEMM + exp-sum + selected logit ----------------
// A: [M][H] bf16 row-major, W: [V][H] bf16 row-major (B^T layout).
// Each block: 128x128 logit tile. 4 waves in 2x2, each 64x64 (4x4 frags of 16x16x32).
__global__ __launch_bounds__(256) void gemm_lse_kernel(
    const unsigned short* __restrict__ A,
    const unsigned short* __restrict__ W,
    const float* __restrict__ bias,
    const int* __restrict__ sel,
    float* __restrict__ partials,     // [M][NCB]
    float* __restrict__ sel_logit)    // [M]
{
    __shared__ unsigned short As[BM * BK];   // 16 KB, linear [row][k]
    __shared__ unsigned short Bs[BN * BK];   // 16 KB
    __shared__ float sums[BM][2];

    const int brow = blockIdx.x;     // 0..31  (consecutive blocks share weight panel)
    const int bcol = blockIdx.y;     // 0..249
    const int tid  = threadIdx.x;
    const int lane = tid & 63;
    const int wave = tid >> 6;
    const int wm = wave >> 1, wn = wave & 1;
    const int l15 = lane & 15, lg = lane >> 4;

    f32x4 acc[4][4] = {};

    const long a_base = (long)brow * BM * H_;
    const long w_base = (long)bcol * BN * H_;

    for (int kt = 0; kt < H_; kt += BK) {
        #pragma unroll
        for (int i = 0; i < 4; ++i) {
            int c = i * 256 + tid;                 // chunk 0..1023 (16B each)
            int r = c >> 3, k8 = (c & 7) * 8;
            gload_lds16(&A[a_base + (long)r * H_ + kt + k8], &As[c * 8]);
            gload_lds16(&W[w_base + (long)r * H_ + kt + k8], &Bs[c * 8]);
        }
        __syncthreads();   // compiler drains vmcnt before s_barrier

        #pragma unroll
        for (int ks = 0; ks < BK; ks += 32) {
            short8 af[4], bfr[4];
            #pragma unroll
            for (int m = 0; m < 4; ++m)
                af[m] = *(const short8*)&As[(wm * 64 + m * 16 + l15) * BK + ks + lg * 8];
            #pragma unroll
            for (int n = 0; n < 4; ++n)
                bfr[n] = *(const short8*)&Bs[(wn * 64 + n * 16 + l15) * BK + ks + lg * 8];
            #pragma unroll
            for (int m = 0; m < 4; ++m)
                #pragma unroll
                for (int n = 0; n < 4; ++n)
                    acc[m][n] = __builtin_amdgcn_mfma_f32_16x16x32_bf16(af[m], bfr[n], acc[m][n], 0, 0, 0);
        }
        __syncthreads();
    }

    // ---- epilogue: bias, exp, per-row partial sums, selected logit ----
    const int col_lo = bcol * BN + wn * 64 + l15;   // + n*16
    float bv[4];
    #pragma unroll
    for (int n = 0; n < 4; ++n) bv[n] = bias[col_lo + n * 16];

    float psum[4][4];
    #pragma unroll
    for (int m = 0; m < 4; ++m) {
        #pragma unroll
        for (int j = 0; j < 4; ++j) {
            const int grow = brow * BM + wm * 64 + m * 16 + lg * 4 + j;
            const int stok = sel[grow];
            float s = 0.f;
            #pragma unroll
            for (int n = 0; n < 4; ++n) {
                float logit = acc[m][n][j] + bv[n];
                s += __expf(logit);
                if (stok == col_lo + n * 16) sel_logit[grow] = logit;
            }
            psum[m][j] = s;
        }
    }
    // reduce across the 16 lanes holding one row's 64 columns of this wave
    #pragma unroll
    for (int m = 0; m < 4; ++m)
        #pragma unroll
        for (int j = 0; j < 4; ++j) {
            float s = psum[m][j];
            s += __shfl_xor(s, 1); s += __shfl_xor(s, 2);
            s += __shfl_xor(s, 4); s += __shfl_xor(s, 8);
            psum[m][j] = s;
        }
    if (l15 == 0) {
        #pragma unroll
        for (int m = 0; m < 4; ++m)
            #pragma unroll
            for (int j = 0; j < 4; ++j)
                sums[wm * 64 + m * 16 + lg * 4 + j][wn] = psum[m][j];
    }
    __syncthreads();
    if (tid < BM) {
        float tot = sums[tid][0] + sums[tid][1];
        partials[(long)(brow * BM + tid) * NCB + bcol] = tot;
    }
}

// ---------------- per-row reduce: partials -> per-token logp ----------------
__global__ void reduce_lse_kernel(const float* __restrict__ partials,
                                  const float* __restrict__ sel_logit,
                                  float* __restrict__ lp) {
    const int row = blockIdx.x;
    const int lane = threadIdx.x;   // 64
    float s = 0.f;
    for (int i = lane; i < NCB; i += 64) s += partials[(long)row * NCB + i];
    #pragma unroll
    for (int o = 32; o; o >>= 1) s += __shfl_xor(s, o);
    if (lane == 0) lp[row] = sel_logit[row] - __logf(s);
}

// ---------------- final GSPO loss (one block) ----------------
__device__ __forceinline__ float block_sum(float v, float* red) {
    const int lane = threadIdx.x & 63, wid = threadIdx.x >> 6;
    #pragma unroll
    for (int o = 32; o; o >>= 1) v += __shfl_xor(v, o);
    if (lane == 0) red[wid] = v;
    __syncthreads();
    if (wid == 0) {
        float x = (lane < 16) ? red[lane] : 0.f;
        #pragma unroll
        for (int o = 8; o; o >>= 1) x += __shfl_xor(x, o);
        if (lane == 0) red[0] = x;
    }
    __syncthreads();
    float r = red[0];
    __syncthreads();
    return r;
}

__global__ __launch_bounds__(1024) void loss_kernel(
    const float* __restrict__ lp, const float* __restrict__ mask,
    const float* __restrict__ adv, const float* __restrict__ ref,
    const float* __restrict__ old, float* __restrict__ out) {
    __shared__ float red[16];
    const int s = threadIdx.x;
    float loss_acc = 0.f;
    for (int b = 0; b < 4; ++b) {
        const int i = b * S_ + s;
        const float mk = mask[i];
        const float lpv = lp[i];
        const float lrsum = block_sum((lpv - old[i]) * mk, red);
        const float msum  = block_sum(mk, red);
        const float seqlen = fmaxf(msum, 1.f);
        const float sw = lrsum / seqlen;            // seq_level_log_weight (fwd value)
        const float c1 = __expf(sw);
        const float c2 = fminf(fmaxf(c1, 1.f - EPS_LOW_C), 1.f + EPS_HIGH_C);
        const float a = adv[b];
        const float pmin = fminf(c1 * a, c2 * a);
        const float d = ref[i] - lpv;
        const float ptl = -pmin + BETA_C * (__expf(d) - d - 1.f);
        const float lsum = block_sum(ptl * mk, red);
        loss_acc += lsum / seqlen;
    }
    if (s == 0) out[0] = loss_acc * (1.f / (float)B_);
}

extern "C" void kernel_launch(void* const* d_in, const int* in_sizes, int n_in,
                              void* d_out, int out_size, void* d_ws, size_t ws_size,
                              hipStream_t stream) {
    const float* x    = (const float*)d_in[0];   // [B,S,H]
    const float* W    = (const float*)d_in[1];   // [V,H]
    const float* bias = (const float*)d_in[2];   // [V]
    const int*   sel  = (const int*)d_in[3];     // [B,S]
    const float* mask = (const float*)d_in[4];   // [B,S]
    const float* adv  = (const float*)d_in[5];   // [B]
    const float* ref  = (const float*)d_in[6];   // [B,S]
    const float* old  = (const float*)d_in[7];   // [B,S]
    float* out = (float*)d_out;

    char* ws = (char*)d_ws;
    unsigned short* Abf = (unsigned short*)ws;                        // 16,777,216 B
    unsigned short* Wbf = (unsigned short*)(ws + 16777216);           // 131,072,000 B
    float* partials  = (float*)(ws + 16777216 + 131072000);           // 4,096,000 B
    float* sel_logit = (float*)(ws + 16777216 + 131072000 + 4096000); // 16,384 B
    float* lp        = sel_logit + M_;                                // 16,384 B

    cvt_kernel<<<2048, 256, 0, stream>>>(x, Abf, M_ * H_ / 4);
    cvt_kernel<<<4096, 256, 0, stream>>>(W, Wbf, V_ * H_ / 4);

    dim3 grid(NRB, NCB);
    gemm_lse_kernel<<<grid, 256, 0, stream>>>(Abf, Wbf, bias, sel, partials, sel_logit);

    reduce_lse_kernel<<<M_, 64, 0, stream>>>(partials, sel_logit, lp);
    loss_kernel<<<1, 1024, 0, stream>>>(lp, mask, adv, ref, old, out);
}

// Round 2
// 625.339 us; speedup vs baseline: 1.4164x; 1.4164x over previous
//
#include <hip/hip_runtime.h>
#include <hip/hip_bf16.h>

#define BETA_C 0.04f
#define EPS_LOW_C 0.2f
#define EPS_HIGH_C 0.2f

static constexpr int B_ = 4, S_ = 1024, H_ = 2048, V_ = 32000;
static constexpr int M_ = B_ * S_;          // 4096 token rows
static constexpr int BM = 256, BN = 256, BK = 64;
static constexpr int NRB = M_ / BM;         // 16
static constexpr int NCB = V_ / BN;         // 125
static constexpr int NT  = H_ / BK;         // 32 K-tiles
static constexpr int NIT = NT / 2;          // 16 iterations (2 K-tiles each)

typedef __attribute__((ext_vector_type(8))) short short8;
typedef __attribute__((ext_vector_type(4))) float f32x4;

__device__ __forceinline__ unsigned short f2bf(float f) {
    unsigned u = __builtin_bit_cast(unsigned, f);
    unsigned r = 0x7FFFu + ((u >> 16) & 1u);
    return (unsigned short)((u + r) >> 16);
}

__device__ __forceinline__ void gload_lds16(const unsigned short* g, unsigned short* l) {
    __builtin_amdgcn_global_load_lds(
        (const __attribute__((address_space(1))) unsigned int*)g,
        (__attribute__((address_space(3))) unsigned int*)l, 16, 0, 0);
}

// ---------------- fp32 -> bf16 conversion ----------------
__global__ void cvt_kernel(const float* __restrict__ in, unsigned short* __restrict__ out, int n4) {
    int i = blockIdx.x * blockDim.x + threadIdx.x;
    int stride = gridDim.x * blockDim.x;
    for (; i < n4; i += stride) {
        float4 v = reinterpret_cast<const float4*>(in)[i];
        ushort4 o;
        o.x = f2bf(v.x); o.y = f2bf(v.y); o.z = f2bf(v.z); o.w = f2bf(v.w);
        reinterpret_cast<ushort4*>(out)[i] = o;
    }
}

// ---------------- 256x256 8-phase fused GEMM + exp-sum + selected logit ----------------
// A: [M][H] bf16, W: [V][H] bf16 (B^T). 8 waves (2x4), per-wave C = 128x64.
// LDS: 2-deep K-tile double buffer, XOR-swizzled (byte ^= (row&7)<<4) on read,
// inverse-swizzled global source feeding linear global_load_lds dests.
__global__ __launch_bounds__(512, 2) void gemm_lse_kernel(
    const unsigned short* __restrict__ A,
    const unsigned short* __restrict__ W,
    const float* __restrict__ bias,
    const int* __restrict__ sel,
    float* __restrict__ partials,     // [M][NCB]
    float* __restrict__ sel_logit)    // [M]
{
    __shared__ unsigned short As[2][BM * BK];   // 64 KB
    __shared__ unsigned short Bs[2][BN * BK];   // 64 KB
    __shared__ float sums[BM][4];               // 4 KB

    const int bid = blockIdx.x;
    const int swz = (bid & 7) * (NRB * NCB / 8) + (bid >> 3);   // 2000 % 8 == 0: bijective
    const int brow = swz % NRB;      // 16 consecutive swz share one W panel
    const int bcol = swz / NRB;
    const int tid  = threadIdx.x;
    const int lane = tid & 63;
    const int wv   = tid >> 6;       // 0..7
    const int wm   = wv >> 2;        // 0..1  (row half)
    const int wn   = wv & 3;         // 0..3  (col quarter)
    const int l15  = lane & 15, lg = lane >> 4;

    const long a_row0 = (long)brow * BM;
    const long w_row0 = (long)bcol * BN;

    // stage one half-tile (128 rows x 64 k) : 2 x global_load_lds per thread.
    // LDS dest linear in tid (required); global source granule pre-swizzled.
    auto stage = [&](const unsigned short* __restrict__ g, long row0,
                     unsigned short* slot, int kt, int half) {
        #pragma unroll
        for (int i = 0; i < 2; ++i) {
            int c = i * 512 + tid;                 // 0..1023
            int r = (c >> 3) + half * 128;         // tile row 0..255
            int gg = (c & 7) ^ (r & 7);            // inverse swizzle on source
            gload_lds16(&g[(row0 + r) * H_ + kt + gg * 8],
                        slot + r * BK + (c & 7) * 8);
        }
    };

    // swizzled fragment read: row-major [row][64] bf16, 16B frag at (ks*32 + lg*8)
    auto rdfrag = [&](const unsigned short* slot, int row, int ks) -> short8 {
        int byte = row * (BK * 2) + ks * 64 + lg * 16;
        byte ^= (row & 7) << 4;
        return *(const short8*)((const char*)slot + byte);
    };

    f32x4 acc[8][4] = {};
    short8 bfr[4][2], af[2][2];

    // prologue: tile0 (A+B) -> buf0, B(tile1) -> buf1. A(tile1) staged at p1-p2.
    stage(A, a_row0, As[0], 0, 0);  stage(A, a_row0, As[0], 0, 1);
    stage(W, w_row0, Bs[0], 0, 0);  stage(W, w_row0, Bs[0], 0, 1);
    stage(W, w_row0, Bs[1], BK, 0); stage(W, w_row0, Bs[1], BK, 1);
    asm volatile("s_waitcnt vmcnt(4)" ::: "memory");   // tile0's 8 loads landed
    __builtin_amdgcn_s_barrier();

#define RD_B(bufi) \
    _Pragma("unroll") \
    for (int n = 0; n < 4; ++n) { \
        int br = wn * 64 + n * 16 + l15; \
        bfr[n][0] = rdfrag(Bs[bufi], br, 0); \
        bfr[n][1] = rdfrag(Bs[bufi], br, 1); \
    }

#define RD_A(bufi, qm) \
    _Pragma("unroll") \
    for (int mi = 0; mi < 2; ++mi) { \
        int ar = wm * 128 + ((qm) * 2 + mi) * 16 + l15; \
        af[mi][0] = rdfrag(As[bufi], ar, 0); \
        af[mi][1] = rdfrag(As[bufi], ar, 1); \
    }

#define MFMA16(qm) \
    __builtin_amdgcn_s_setprio(1); \
    _Pragma("unroll") \
    for (int mi = 0; mi < 2; ++mi) \
    _Pragma("unroll") \
    for (int n = 0; n < 4; ++n) \
    _Pragma("unroll") \
    for (int ks = 0; ks < 2; ++ks) \
        acc[(qm) * 2 + mi][n] = __builtin_amdgcn_mfma_f32_16x16x32_bf16( \
            af[mi][ks], bfr[n][ks], acc[(qm) * 2 + mi][n], 0, 0, 0); \
    __builtin_amdgcn_s_setprio(0);

#define BARRIER_LGKM() \
    __builtin_amdgcn_s_barrier(); \
    asm volatile("s_waitcnt lgkmcnt(0)" ::: "memory"); \
    __builtin_amdgcn_sched_barrier(0);

    for (int it = 0; it < NIT; ++it) {
        const int t = 2 * it;
        const int kt1 = ((t + 1) & (NT - 1)) * BK;
        const int kt2 = ((t + 2) & (NT - 1)) * BK;
        const int kt3 = ((t + 3) & (NT - 1)) * BK;

        // ---- tile t (buf0) ----
        // p1: qm0; stage Ah0(t+1)->buf1 (A(t-1) freed at prev p8)
        RD_B(0) RD_A(0, 0)
        stage(A, a_row0, As[1], kt1, 0);
        BARRIER_LGKM()
        MFMA16(0)
        __builtin_amdgcn_s_barrier();
        // p2: qm1; stage Ah1(t+1)
        RD_A(0, 1)
        stage(A, a_row0, As[1], kt1, 1);
        BARRIER_LGKM()
        MFMA16(1)
        __builtin_amdgcn_s_barrier();
        // p3: qm2; stage Bh0(t+2)->buf0 (B(t) fully read at p1)
        RD_A(0, 2)
        stage(W, w_row0, Bs[0], kt2, 0);
        BARRIER_LGKM()
        MFMA16(2)
        __builtin_amdgcn_s_barrier();
        // p4: qm3; stage Bh1(t+2); counted wait: only B(t+2) (4 ops) may stay in flight
        RD_A(0, 3)
        stage(W, w_row0, Bs[0], kt2, 1);
        BARRIER_LGKM()
        MFMA16(3)
        asm volatile("s_waitcnt vmcnt(4)" ::: "memory");
        __builtin_amdgcn_s_barrier();

        // ---- tile t+1 (buf1) ----
        // p5: qm0; stage Ah0(t+2)->buf0 (A(t) freed at p4)
        RD_B(1) RD_A(1, 0)
        stage(A, a_row0, As[0], kt2, 0);
        BARRIER_LGKM()
        MFMA16(0)
        __builtin_amdgcn_s_barrier();
        // p6: qm1; stage Ah1(t+2)
        RD_A(1, 1)
        stage(A, a_row0, As[0], kt2, 1);
        BARRIER_LGKM()
        MFMA16(1)
        __builtin_amdgcn_s_barrier();
        // p7: qm2; stage Bh0(t+3)->buf1 (B(t+1) fully read at p5)
        RD_A(1, 2)
        stage(W, w_row0, Bs[1], kt3, 0);
        BARRIER_LGKM()
        MFMA16(2)
        __builtin_amdgcn_s_barrier();
        // p8: qm3; stage Bh1(t+3); counted wait
        RD_A(1, 3)
        stage(W, w_row0, Bs[1], kt3, 1);
        BARRIER_LGKM()
        MFMA16(3)
        asm volatile("s_waitcnt vmcnt(4)" ::: "memory");
        __builtin_amdgcn_s_barrier();
    }

    asm volatile("s_waitcnt vmcnt(0)" ::: "memory");  // drain stray wrap-around stages

    // ---- epilogue: bias, exp, per-row partial sums, selected logit ----
    const int colb = bcol * BN + wn * 64 + l15;       // + n*16
    float bv[4];
    #pragma unroll
    for (int n = 0; n < 4; ++n) bv[n] = bias[colb + n * 16];

    #pragma unroll
    for (int m = 0; m < 8; ++m) {
        #pragma unroll
        for (int j = 0; j < 4; ++j) {
            const long grow = (long)brow * BM + wm * 128 + m * 16 + lg * 4 + j;
            const int stok = sel[grow];
            float s = 0.f;
            #pragma unroll
            for (int n = 0; n < 4; ++n) {
                float logit = acc[m][n][j] + bv[n];
                s += __expf(logit);
                if (stok == colb + n * 16) sel_logit[grow] = logit;
            }
            s += __shfl_xor(s, 1); s += __shfl_xor(s, 2);
            s += __shfl_xor(s, 4); s += __shfl_xor(s, 8);
            if (l15 == 0) sums[wm * 128 + m * 16 + lg * 4 + j][wn] = s;
        }
    }
    __syncthreads();
    if (tid < BM) {
        float tot = sums[tid][0] + sums[tid][1] + sums[tid][2] + sums[tid][3];
        partials[((long)brow * BM + tid) * NCB + bcol] = tot;
    }
#undef RD_B
#undef RD_A
#undef MFMA16
#undef BARRIER_LGKM
}

// ---------------- per-row reduce: partials -> per-token logp ----------------
__global__ void reduce_lse_kernel(const float* __restrict__ partials,
                                  const float* __restrict__ sel_logit,
                                  float* __restrict__ lp) {
    const int row = blockIdx.x;
    const int lane = threadIdx.x;   // 64
    float s = 0.f;
    for (int i = lane; i < NCB; i += 64) s += partials[(long)row * NCB + i];
    #pragma unroll
    for (int o = 32; o; o >>= 1) s += __shfl_xor(s, o);
    if (lane == 0) lp[row] = sel_logit[row] - __logf(s);
}

// ---------------- final GSPO loss (one block) ----------------
__device__ __forceinline__ float block_sum(float v, float* red) {
    const int lane = threadIdx.x & 63, wid = threadIdx.x >> 6;
    #pragma unroll
    for (int o = 32; o; o >>= 1) v += __shfl_xor(v, o);
    if (lane == 0) red[wid] = v;
    __syncthreads();
    if (wid == 0) {
        float x = (lane < 16) ? red[lane] : 0.f;
        #pragma unroll
        for (int o = 8; o; o >>= 1) x += __shfl_xor(x, o);
        if (lane == 0) red[0] = x;
    }
    __syncthreads();
    float r = red[0];
    __syncthreads();
    return r;
}

__global__ __launch_bounds__(1024) void loss_kernel(
    const float* __restrict__ lp, const float* __restrict__ mask,
    const float* __restrict__ adv, const float* __restrict__ ref,
    const float* __restrict__ old, float* __restrict__ out) {
    __shared__ float red[16];
    const int s = threadIdx.x;
    float loss_acc = 0.f;
    for (int b = 0; b < 4; ++b) {
        const int i = b * S_ + s;
        const float mk = mask[i];
        const float lpv = lp[i];
        const float lrsum = block_sum((lpv - old[i]) * mk, red);
        const float msum  = block_sum(mk, red);
        const float seqlen = fmaxf(msum, 1.f);
        const float sw = lrsum / seqlen;
        const float c1 = __expf(sw);
        const float c2 = fminf(fmaxf(c1, 1.f - EPS_LOW_C), 1.f + EPS_HIGH_C);
        const float a = adv[b];
        const float pmin = fminf(c1 * a, c2 * a);
        const float d = ref[i] - lpv;
        const float ptl = -pmin + BETA_C * (__expf(d) - d - 1.f);
        const float lsum = block_sum(ptl * mk, red);
        loss_acc += lsum / seqlen;
    }
    if (s == 0) out[0] = loss_acc * (1.f / (float)B_);
}

extern "C" void kernel_launch(void* const* d_in, const int* in_sizes, int n_in,
                              void* d_out, int out_size, void* d_ws, size_t ws_size,
                              hipStream_t stream) {
    const float* x    = (const float*)d_in[0];
    const float* W    = (const float*)d_in[1];
    const float* bias = (const float*)d_in[2];
    const int*   sel  = (const int*)d_in[3];
    const float* mask = (const float*)d_in[4];
    const float* adv  = (const float*)d_in[5];
    const float* ref  = (const float*)d_in[6];
    const float* old  = (const float*)d_in[7];
    float* out = (float*)d_out;

    char* ws = (char*)d_ws;
    unsigned short* Abf = (unsigned short*)ws;                        // 16,777,216 B
    unsigned short* Wbf = (unsigned short*)(ws + 16777216);           // 131,072,000 B
    float* partials  = (float*)(ws + 16777216 + 131072000);           // 2,048,000 B
    float* sel_logit = (float*)(ws + 16777216 + 131072000 + 2048000);
    float* lp        = sel_logit + M_;

    cvt_kernel<<<2048, 256, 0, stream>>>(x, Abf, M_ * H_ / 4);
    cvt_kernel<<<4096, 256, 0, stream>>>(W, Wbf, V_ * H_ / 4);

    gemm_lse_kernel<<<NRB * NCB, 512, 0, stream>>>(Abf, Wbf, bias, sel, partials, sel_logit);

    reduce_lse_kernel<<<M_, 64, 0, stream>>>(partials, sel_logit, lp);
    loss_kernel<<<1, 1024, 0, stream>>>(lp, mask, adv, ref, old, out);
}